// Round 1
// baseline (246.981 us; speedup 1.0000x reference)
//
#include <hip/hip_runtime.h>
#include <math.h>

// Problem constants (fixed by setup_inputs): T=4096, V=32000, NB=2048.
#define VDIM 32000
#define VEC4 (VDIM / 4)   // 8000
#define NCHUNK 64

// ---------------------------------------------------------------------------
// Kernel 1: per-row online logsumexp + gather of the c[] columns.
// One block per row t. Streams the 128 KB row once (float4), computes
// lse[t] via online (m,s), writes blank[t] = row[V-1]-lse and the
// normalized gather matrix gbuf[t][b] = row[c[b]] - lse (coalesced).
// ---------------------------------------------------------------------------
__global__ __launch_bounds__(256) void row_lse_gather(
    const float* __restrict__ prob, const int* __restrict__ c,
    float* __restrict__ gbuf, float* __restrict__ blanklp, int NB)
{
    const int t   = blockIdx.x;
    const int tid = threadIdx.x;
    const float* row = prob + (size_t)t * VDIM;
    const float4* vrow = (const float4*)row;

    float m = -INFINITY, s = 0.0f;
    for (int i = tid; i < VEC4; i += 256) {
        float4 v = vrow[i];
        float xs[4] = {v.x, v.y, v.z, v.w};
#pragma unroll
        for (int j = 0; j < 4; ++j) {
            float x  = xs[j];
            float mn = fmaxf(m, x);
            s = s * __expf(m - mn) + __expf(x - mn);
            m = mn;
        }
    }
    // wave(64) butterfly reduce of (m,s)
#pragma unroll
    for (int off = 32; off > 0; off >>= 1) {
        float mo = __shfl_xor(m, off);
        float so = __shfl_xor(s, off);
        float mn = fmaxf(m, mo);
        s = s * __expf(m - mn) + so * __expf(mo - mn);
        m = mn;
    }
    __shared__ float sm[4], ss[4], slse;
    const int wave = tid >> 6;
    if ((tid & 63) == 0) { sm[wave] = m; ss[wave] = s; }
    __syncthreads();
    if (tid == 0) {
        float M = sm[0], S = ss[0];
#pragma unroll
        for (int w = 1; w < 4; ++w) {
            float mn = fmaxf(M, sm[w]);
            S = S * __expf(M - mn) + ss[w] * __expf(sm[w] - mn);
            M = mn;
        }
        float lse = M + __logf(S);
        slse = lse;
        blanklp[t] = row[VDIM - 1] - lse;
    }
    __syncthreads();
    const float lse = slse;
    // gather: row is hot in this XCD's L2 (128 KB << 4 MB)
    for (int b = tid; b < NB; b += 256) {
        gbuf[(size_t)t * NB + b] = row[c[b]] - lse;
    }
}

// ---------------------------------------------------------------------------
// Kernel 2: inclusive cumsum of blank[0..T) -> cb[0..T). T == 4096 == 1024*4.
// Single block, thread-local prefix of 4 + Hillis-Steele over 1024 totals.
// ---------------------------------------------------------------------------
__global__ __launch_bounds__(1024) void scan_cb(
    const float* __restrict__ bl, float* __restrict__ cb, int T)
{
    __shared__ float tot[1024];
    const int tid  = threadIdx.x;
    const int base = tid * 4;
    float v[4];
    float run = 0.0f;
#pragma unroll
    for (int j = 0; j < 4; ++j) {
        float x = (base + j < T) ? bl[base + j] : 0.0f;
        run += x;
        v[j] = run;
    }
    tot[tid] = run;
    __syncthreads();
    for (int off = 1; off < 1024; off <<= 1) {
        float add = (tid >= off) ? tot[tid - off] : 0.0f;
        __syncthreads();
        tot[tid] += add;
        __syncthreads();
    }
    const float offset = (tid == 0) ? 0.0f : tot[tid - 1];
#pragma unroll
    for (int j = 0; j < 4; ++j) {
        if (base + j < T) cb[base + j] = v[j] + offset;
    }
}

// ---------------------------------------------------------------------------
// Kernel 3: partial streaming logsumexp over a t-chunk for 256 beams/block.
// blockIdx = ch * (NB/256) + grp. Thread j owns beam b = grp*256+j, so the
// gbuf[t][b] loads are fully coalesced. cb[t-1] is a uniform broadcast load.
// ---------------------------------------------------------------------------
__global__ __launch_bounds__(256) void partial_lse(
    const float* __restrict__ gbuf, const float* __restrict__ cb,
    float* __restrict__ pm, float* __restrict__ ps,
    int NB, int T, int tstart, int tper)
{
    const int nb_groups = NB >> 8;
    const int grp = blockIdx.x % nb_groups;
    const int ch  = blockIdx.x / nb_groups;
    const int b   = (grp << 8) + threadIdx.x;
    const int t0  = tstart + ch * tper;
    const int t1  = min(t0 + tper, T);

    float m = -INFINITY, s = 0.0f;
    for (int t = t0; t < t1; ++t) {
        float x  = gbuf[(size_t)t * NB + b] + cb[t - 1];
        float mn = fmaxf(m, x);
        s = s * __expf(m - mn) + __expf(x - mn);
        m = mn;
    }
    pm[ch * NB + b] = m;
    ps[ch * NB + b] = s;
}

// ---------------------------------------------------------------------------
// Kernel 4: combine NCHUNK partials per beam; eos (c==1) override; write out.
// ---------------------------------------------------------------------------
__global__ __launch_bounds__(256) void final_score(
    const float* __restrict__ pm, const float* __restrict__ ps,
    const float* __restrict__ cb, const int* __restrict__ c,
    float* __restrict__ out, int NB, int T, int nchunk)
{
    const int b = blockIdx.x * 256 + threadIdx.x;
    if (b >= NB) return;
    float m = -INFINITY, s = 0.0f;
    for (int ch = 0; ch < nchunk; ++ch) {
        float mo = pm[ch * NB + b];
        float so = ps[ch * NB + b];
        float mn = fmaxf(m, mo);
        s = s * __expf(m - mn) + so * __expf(mo - mn);
        m = mn;
    }
    float score = m + __logf(s);
    if (c[b] == 1) score = cb[T - 1];   // eos -> gamma_nb_g = cb[-1]
    out[b] = score;
}

extern "C" void kernel_launch(void* const* d_in, const int* in_sizes, int n_in,
                              void* d_out, int out_size, void* d_ws, size_t ws_size,
                              hipStream_t stream)
{
    const float* prob = (const float*)d_in[0];
    // d_in[1] (g) is dead code in the reference (its only consumer, `repeat`,
    // multiplies into a constant NEG_INF term).
    const int* c = (const int*)d_in[2];

    const int T  = in_sizes[0] / VDIM;   // 4096
    const int NB = in_sizes[2];          // 2048
    const int N  = NB / 64;              // ctc_beam = 64 (fixed in setup)
    const int U  = in_sizes[1] / N;      // 12
    const int glen   = U - 1;            // 11
    const int tstart = glen > 1 ? glen : 1;

    // workspace layout
    char*  ws      = (char*)d_ws;
    float* gbuf    = (float*)ws;                         // T*NB floats
    size_t gbytes  = (size_t)T * NB * sizeof(float);
    float* blanklp = (float*)(ws + gbytes);              // T floats
    float* cb      = blanklp + T;                        // T floats
    float* pm      = cb + T;                             // NCHUNK*NB floats
    float* ps      = pm + (size_t)NCHUNK * NB;           // NCHUNK*NB floats
    size_t need    = gbytes + 2 * (size_t)T * 4 + 2 * (size_t)NCHUNK * NB * 4;
    if (ws_size < need) return;  // fail visibly (output stays poisoned)

    const int tper = (T - tstart + NCHUNK - 1) / NCHUNK; // 64

    row_lse_gather<<<T, 256, 0, stream>>>(prob, c, gbuf, blanklp, NB);
    scan_cb<<<1, 1024, 0, stream>>>(blanklp, cb, T);
    partial_lse<<<NCHUNK * (NB / 256), 256, 0, stream>>>(gbuf, cb, pm, ps, NB, T, tstart, tper);
    final_score<<<NB / 256, 256, 0, stream>>>(pm, ps, cb, c, (float*)d_out, NB, T, NCHUNK);
}

// Round 2
// 170.547 us; speedup vs baseline: 1.4482x; 1.4482x over previous
//
#include <hip/hip_runtime.h>
#include <math.h>

// Problem constants (fixed by setup_inputs): T=4096, V=32000, NB=2048.
#define VDIM  32000
#define HALF  16000          // elements per LDS-staged half (64 KB)
#define HVEC4 (HALF / 4)     // 4000 float4 per half
#define NCHUNK 64

// ---------------------------------------------------------------------------
// Kernel 1: per-row LSE + raw gather, LDS-staged in two 64 KB halves.
// One block per row t, 1024 threads, 64 KB static LDS -> 2 blocks/CU.
// Streams the row once (float4) into LDS while accumulating online (m,s);
// after each half is staged, gathers the c[b] falling in that half as RAW
// values (lse subtraction deferred to kernel 3). Writes lse[t] and the raw
// blank logit row[V-1].
// ---------------------------------------------------------------------------
__global__ __launch_bounds__(1024) void row_stage_gather(
    const float* __restrict__ prob, const int* __restrict__ c,
    float* __restrict__ graw, float* __restrict__ lse_arr,
    float* __restrict__ blankraw, int NB)
{
    __shared__ float half_buf[HALF];       // 64000 B
    __shared__ float sm[16], ss[16];
    const int t   = blockIdx.x;
    const int tid = threadIdx.x;
    const float4* vrow = (const float4*)(prob + (size_t)t * VDIM);
    float4* vlds = (float4*)half_buf;

    float m = -INFINITY, s = 0.0f;

    // ---- pass 0: elements [0, HALF) ----
    for (int i = tid; i < HVEC4; i += 1024) {
        float4 v = vrow[i];
        vlds[i] = v;
        float xs[4] = {v.x, v.y, v.z, v.w};
#pragma unroll
        for (int j = 0; j < 4; ++j) {
            float x  = xs[j];
            float mn = fmaxf(m, x);
            s = s * __expf(m - mn) + __expf(x - mn);
            m = mn;
        }
    }
    __syncthreads();
    for (int b = tid; b < NB; b += 1024) {
        int pos = c[b];
        if (pos < HALF) graw[(size_t)t * NB + b] = half_buf[pos];
    }
    __syncthreads();   // gather done before overwrite

    // ---- pass 1: elements [HALF, VDIM) ----
    for (int i = tid; i < HVEC4; i += 1024) {
        float4 v = vrow[HVEC4 + i];
        vlds[i] = v;
        float xs[4] = {v.x, v.y, v.z, v.w};
#pragma unroll
        for (int j = 0; j < 4; ++j) {
            float x  = xs[j];
            float mn = fmaxf(m, x);
            s = s * __expf(m - mn) + __expf(x - mn);
            m = mn;
        }
    }
    __syncthreads();
    for (int b = tid; b < NB; b += 1024) {
        int pos = c[b];
        if (pos >= HALF) graw[(size_t)t * NB + b] = half_buf[pos - HALF];
    }

    // ---- block-wide (m,s) reduction -> lse ----
#pragma unroll
    for (int off = 32; off > 0; off >>= 1) {
        float mo = __shfl_xor(m, off);
        float so = __shfl_xor(s, off);
        float mn = fmaxf(m, mo);
        s = s * __expf(m - mn) + so * __expf(mo - mn);
        m = mn;
    }
    const int wave = tid >> 6;
    if ((tid & 63) == 0) { sm[wave] = m; ss[wave] = s; }
    __syncthreads();
    if (tid == 0) {
        float M = sm[0], S = ss[0];
#pragma unroll
        for (int w = 1; w < 16; ++w) {
            float mn = fmaxf(M, sm[w]);
            S = S * __expf(M - mn) + ss[w] * __expf(sm[w] - mn);
            M = mn;
        }
        lse_arr[t]  = M + __logf(S);
        blankraw[t] = half_buf[HALF - 1];   // element VDIM-1 lives in pass-1 half
    }
}

// ---------------------------------------------------------------------------
// Kernel 2: blank[t] = blankraw[t]-lse[t]; cb = cumsum(blank);
// addc[t] = cb[t-1] - lse[t]  (the per-t constant kernel 3 adds).
// Single block, T == 4096 == 1024*4.
// ---------------------------------------------------------------------------
__global__ __launch_bounds__(1024) void scan_cb(
    const float* __restrict__ blankraw, const float* __restrict__ lse_arr,
    float* __restrict__ cb, float* __restrict__ addc, int T)
{
    __shared__ float tot[1024];
    const int tid  = threadIdx.x;
    const int base = tid * 4;
    float v[4];
    float run = 0.0f;
#pragma unroll
    for (int j = 0; j < 4; ++j) {
        float x = blankraw[base + j] - lse_arr[base + j];
        run += x;
        v[j] = run;
    }
    tot[tid] = run;
    __syncthreads();
    for (int off = 1; off < 1024; off <<= 1) {
        float add = (tid >= off) ? tot[tid - off] : 0.0f;
        __syncthreads();
        tot[tid] += add;
        __syncthreads();
    }
    const float offset = (tid == 0) ? 0.0f : tot[tid - 1];
#pragma unroll
    for (int j = 0; j < 4; ++j) {
        float cbv = v[j] + offset;
        cb[base + j] = cbv;
        // addc[t] = cb[t-1] - lse[t]; cb[t-1] = cbv - blank[t]
        float cbm1 = cbv - (blankraw[base + j] - lse_arr[base + j]);
        addc[base + j] = cbm1 - lse_arr[base + j];
    }
}

// ---------------------------------------------------------------------------
// Kernel 3: partial streaming logsumexp over a t-chunk for 256 beams/block.
// x = graw[t][b] + addc[t]  ( = row[c[b]] - lse[t] + cb[t-1] )
// ---------------------------------------------------------------------------
__global__ __launch_bounds__(256) void partial_lse(
    const float* __restrict__ graw, const float* __restrict__ addc,
    float* __restrict__ pm, float* __restrict__ ps,
    int NB, int T, int tstart, int tper)
{
    const int nb_groups = NB >> 8;
    const int grp = blockIdx.x % nb_groups;
    const int ch  = blockIdx.x / nb_groups;
    const int b   = (grp << 8) + threadIdx.x;
    const int t0  = tstart + ch * tper;
    const int t1  = min(t0 + tper, T);

    float m = -INFINITY, s = 0.0f;
    for (int t = t0; t < t1; ++t) {
        float x  = graw[(size_t)t * NB + b] + addc[t];
        float mn = fmaxf(m, x);
        s = s * __expf(m - mn) + __expf(x - mn);
        m = mn;
    }
    pm[ch * NB + b] = m;
    ps[ch * NB + b] = s;
}

// ---------------------------------------------------------------------------
// Kernel 4: combine NCHUNK partials per beam; eos (c==1) override; write out.
// ---------------------------------------------------------------------------
__global__ __launch_bounds__(256) void final_score(
    const float* __restrict__ pm, const float* __restrict__ ps,
    const float* __restrict__ cb, const int* __restrict__ c,
    float* __restrict__ out, int NB, int T, int nchunk)
{
    const int b = blockIdx.x * 256 + threadIdx.x;
    if (b >= NB) return;
    float m = -INFINITY, s = 0.0f;
    for (int ch = 0; ch < nchunk; ++ch) {
        float mo = pm[ch * NB + b];
        float so = ps[ch * NB + b];
        float mn = fmaxf(m, mo);
        s = s * __expf(m - mn) + so * __expf(mo - mn);
        m = mn;
    }
    float score = m + __logf(s);
    if (c[b] == 1) score = cb[T - 1];   // eos -> gamma_nb_g = cb[-1]
    out[b] = score;
}

extern "C" void kernel_launch(void* const* d_in, const int* in_sizes, int n_in,
                              void* d_out, int out_size, void* d_ws, size_t ws_size,
                              hipStream_t stream)
{
    const float* prob = (const float*)d_in[0];
    // d_in[1] (g) is dead code in the reference (its only consumer, `repeat`,
    // feeds a term that is constant NEG_INF).
    const int* c = (const int*)d_in[2];

    const int T  = in_sizes[0] / VDIM;   // 4096
    const int NB = in_sizes[2];          // 2048
    const int N  = NB / 64;              // ctc_beam = 64 (fixed in setup)
    const int U  = in_sizes[1] / N;      // 12
    const int glen   = U - 1;            // 11
    const int tstart = glen > 1 ? glen : 1;

    // workspace layout
    char*  ws       = (char*)d_ws;
    float* graw     = (float*)ws;                        // T*NB
    size_t gbytes   = (size_t)T * NB * sizeof(float);
    float* lse_arr  = (float*)(ws + gbytes);             // T
    float* blankraw = lse_arr + T;                       // T
    float* cb       = blankraw + T;                      // T
    float* addc     = cb + T;                            // T
    float* pm       = addc + T;                          // NCHUNK*NB
    float* ps       = pm + (size_t)NCHUNK * NB;          // NCHUNK*NB
    size_t need     = gbytes + 4 * (size_t)T * 4 + 2 * (size_t)NCHUNK * NB * 4;
    if (ws_size < need) return;  // fail visibly (output stays poisoned)

    const int tper = (T - tstart + NCHUNK - 1) / NCHUNK; // 64

    row_stage_gather<<<T, 1024, 0, stream>>>(prob, c, graw, lse_arr, blankraw, NB);
    scan_cb<<<1, 1024, 0, stream>>>(blankraw, lse_arr, cb, addc, T);
    partial_lse<<<NCHUNK * (NB / 256), 256, 0, stream>>>(graw, addc, pm, ps, NB, T, tstart, tper);
    final_score<<<NB / 256, 256, 0, stream>>>(pm, ps, cb, c, (float*)d_out, NB, T, NCHUNK);
}